// Round 1
// baseline (11.345 us; speedup 1.0000x reference)
//
#include <hip/hip_runtime.h>
#include <math.h>

// out = sigmoid( ts^2 * sum_b ( dot(graph_state_b, W) + bias )^2 )
// graph_state_b[f] = h0 * sum_{all n} x[b,n,f]
//                  + (h1*(nn-1) + h2*(nn-1)^2) * sum_{n < nn} x[b,n,f]
// derived from U p(L) U^T == p(A) = h0 I + h1 A + h2 A^2,
// A = J - I on the valid block, A^2 = (nn-2) J + I there.

__global__ __launch_bounds__(256) void sgc_batch_kernel(
    const float* __restrict__ x,
    const int*   __restrict__ nnodes,
    const float* __restrict__ h,
    const float* __restrict__ W,
    const float* __restrict__ bias,
    float*       __restrict__ partial,
    int B, int N, int F)
{
    const int wave = threadIdx.x >> 6;   // 4 waves per block
    const int lane = threadIdx.x & 63;   // lane = node index
    const int b    = blockIdx.x * 4 + wave;

    __shared__ float sblk[4];
    float sq = 0.0f;

    if (b < B) {
        const float h0 = h[0], h1 = h[1], h2 = h[2];
        const int   nv = nnodes[b];                 // wave-uniform
        const float m  = (float)(nv - 1);
        const float c1 = h1 * m + h2 * m * m;

        float d = 0.0f;
        if (lane < N) {
            const float* xp = x + ((size_t)b * N + lane) * F;
            #pragma unroll 7
            for (int f = 0; f < F; ++f) d += xp[f] * W[f];
            d *= h0 + ((lane < nv) ? c1 : 0.0f);
        }
        #pragma unroll
        for (int off = 32; off > 0; off >>= 1)
            d += __shfl_down(d, off, 64);

        if (lane == 0) {
            const float ob = d + bias[0];
            sq = ob * ob;
        }
    }
    if (lane == 0) sblk[wave] = sq;
    __syncthreads();
    if (threadIdx.x == 0)
        partial[blockIdx.x] = sblk[0] + sblk[1] + sblk[2] + sblk[3];
}

__global__ __launch_bounds__(1024) void sgc_final_kernel(
    const float* __restrict__ partial, int nPartial,
    const float* __restrict__ ts,
    float*       __restrict__ out)
{
    __shared__ float s[16];
    const int wave = threadIdx.x >> 6;
    const int lane = threadIdx.x & 63;

    float v = 0.0f;
    for (int i = threadIdx.x; i < nPartial; i += 1024) v += partial[i];
    #pragma unroll
    for (int off = 32; off > 0; off >>= 1)
        v += __shfl_down(v, off, 64);

    if (lane == 0) s[wave] = v;
    __syncthreads();
    if (threadIdx.x == 0) {
        float total = 0.0f;
        #pragma unroll
        for (int w = 0; w < 16; ++w) total += s[w];
        const float t   = ts[0];
        const float arg = t * t * total;   // >= 0 always
        out[0] = 1.0f / (1.0f + expf(-arg));
    }
}

extern "C" void kernel_launch(void* const* d_in, const int* in_sizes, int n_in,
                              void* d_out, int out_size, void* d_ws, size_t ws_size,
                              hipStream_t stream) {
    const float* x    = (const float*)d_in[0];
    const int*   nn   = (const int*)  d_in[1];
    const float* h    = (const float*)d_in[2];
    const float* W    = (const float*)d_in[3];
    const float* bias = (const float*)d_in[4];
    const float* ts   = (const float*)d_in[5];

    const int B = in_sizes[1];            // number_of_nodes has B entries
    const int F = in_sizes[3];            // W has F entries
    const int N = in_sizes[0] / (B * F);  // x is [B, N, F]

    float* partial = (float*)d_ws;
    const int grid = (B + 3) / 4;         // 4 batches (waves) per block

    sgc_batch_kernel<<<grid, 256, 0, stream>>>(x, nn, h, W, bias, partial, B, N, F);
    sgc_final_kernel<<<1, 1024, 0, stream>>>(partial, grid, ts, (float*)d_out);
}